// Round 3
// baseline (48.305 us; speedup 1.0000x reference)
//
#include <hip/hip_runtime.h>

#define QN_F (-127.0f)
#define QP_F (127.0f)
#define MSB 128

typedef float f32x4 __attribute__((ext_vector_type(4)));

__global__ void quant_main_kernel(const f32x4* __restrict__ w4,
                                  const float* __restrict__ alpha,
                                  f32x4* __restrict__ out4,
                                  int n4) {
    const float a = fmaxf(alpha[0], 1e-4f);
    int idx = blockIdx.x * blockDim.x + threadIdx.x;
    const int stride = gridDim.x * blockDim.x;
    #pragma unroll 4
    for (int i = idx; i < n4; i += stride) {
        f32x4 v = w4[i];                 // regular load: keep weight hot in L2/L3
        f32x4 r;
        r.x = rintf(fminf(fmaxf(v.x / a, QN_F), QP_F)) * a;
        r.y = rintf(fminf(fmaxf(v.y / a, QN_F), QP_F)) * a;
        r.z = rintf(fminf(fmaxf(v.z / a, QN_F), QP_F)) * a;
        r.w = rintf(fminf(fmaxf(v.w / a, QN_F), QP_F)) * a;
        // non-temporal: streamed output, never re-read — don't evict the weight
        __builtin_nontemporal_store(r, &out4[i]);
    }
}

__global__ void flip_fixup_kernel(const float* __restrict__ w,
                                  const float* __restrict__ alpha,
                                  const int* __restrict__ flip_idx,
                                  float* __restrict__ out,
                                  int nf) {
    const float a = fmaxf(alpha[0], 1e-4f);
    int t = blockIdx.x * blockDim.x + threadIdx.x;
    if (t < nf) {
        int i = flip_idx[t];
        float q = fminf(fmaxf(w[i] / a, QN_F), QP_F);
        int qi = (int)q;      // truncation toward zero == astype(int32)
        qi ^= MSB;            // full-width int32 XOR, matches numpy bitwise_xor
        out[i] = (float)qi * a;   // round(float(qi)) == float(qi), then * a
    }
}

extern "C" void kernel_launch(void* const* d_in, const int* in_sizes, int n_in,
                              void* d_out, int out_size, void* d_ws, size_t ws_size,
                              hipStream_t stream) {
    const float* w = (const float*)d_in[0];
    const float* alpha = (const float*)d_in[1];
    const int* flip_idx = (const int*)d_in[2];   // harness passes integers as int32
    float* out = (float*)d_out;

    const int n = in_sizes[0];          // 33554432
    const int nf = in_sizes[2];         // 3356
    const int n4 = n / 4;

    const int block = 256;
    int grid = (n4 + block - 1) / block;
    if (grid > 2048) grid = 2048;       // grid-stride the rest
    quant_main_kernel<<<grid, block, 0, stream>>>(
        (const f32x4*)w, alpha, (f32x4*)out, n4);

    int fgrid = (nf + block - 1) / block;
    flip_fixup_kernel<<<fgrid, block, 0, stream>>>(w, alpha, flip_idx, out, nf);
}

// Round 4
// 47.945 us; speedup vs baseline: 1.0075x; 1.0075x over previous
//
#include <hip/hip_runtime.h>

#define QN_F (-127.0f)
#define QP_F (127.0f)
#define MSB 128

typedef float f32x4 __attribute__((ext_vector_type(4)));

// Single fused kernel. Block-contiguous partition so each flip index is owned
// by exactly one block; block applies its own flips after __syncthreads()
// (compiler emits s_waitcnt vmcnt(0) before s_barrier, so main-phase stores
// are drained before the flip overwrites).
__global__ void quant_fused_kernel(const float* __restrict__ w,
                                   const float* __restrict__ alpha,
                                   const int* __restrict__ flip_idx,
                                   float* __restrict__ out,
                                   int n4, int nf) {
    const float a = fmaxf(alpha[0], 1e-4f);

    // contiguous chunk of float4s per block
    const int per_block = (n4 + gridDim.x - 1) / gridDim.x;
    const int lo4 = blockIdx.x * per_block;
    const int hi4 = min(lo4 + per_block, n4);

    const f32x4* __restrict__ w4 = (const f32x4*)w;
    f32x4* __restrict__ out4 = (f32x4*)out;

    #pragma unroll 4
    for (int i = lo4 + (int)threadIdx.x; i < hi4; i += (int)blockDim.x) {
        f32x4 v = w4[i];
        f32x4 r;
        r.x = rintf(fminf(fmaxf(v.x / a, QN_F), QP_F)) * a;
        r.y = rintf(fminf(fmaxf(v.y / a, QN_F), QP_F)) * a;
        r.z = rintf(fminf(fmaxf(v.z / a, QN_F), QP_F)) * a;
        r.w = rintf(fminf(fmaxf(v.w / a, QN_F), QP_F)) * a;
        __builtin_nontemporal_store(r, &out4[i]);
    }

    __syncthreads();   // drains vmcnt: main-phase stores ordered before flips

    // flip-scan phase: only flips inside this block's float range
    const int loF = lo4 * 4;
    const int hiF = hi4 * 4;
    for (int t = (int)threadIdx.x; t < nf; t += (int)blockDim.x) {
        int i = flip_idx[t];
        if (i >= loF && i < hiF) {
            float q = fminf(fmaxf(w[i] / a, QN_F), QP_F);
            int qi = (int)q;   // trunc toward zero == astype(int32)
            qi ^= MSB;         // full-width int32 XOR == numpy bitwise_xor
            out[i] = (float)qi * a;   // round(int) == int, then * a
        }
    }
}

extern "C" void kernel_launch(void* const* d_in, const int* in_sizes, int n_in,
                              void* d_out, int out_size, void* d_ws, size_t ws_size,
                              hipStream_t stream) {
    const float* w = (const float*)d_in[0];
    const float* alpha = (const float*)d_in[1];
    const int* flip_idx = (const int*)d_in[2];   // harness passes integers as int32
    float* out = (float*)d_out;

    const int n = in_sizes[0];          // 33554432
    const int nf = in_sizes[2];         // 3356
    const int n4 = n / 4;               // 8388608 float4s

    const int block = 256;
    const int grid = 2048;              // 4096 float4s per block, 16 per thread
    quant_fused_kernel<<<grid, block, 0, stream>>>(w, alpha, flip_idx, out, n4, nf);
}